// Round 5
// baseline (398.849 us; speedup 1.0000x reference)
//
#include <hip/hip_runtime.h>
#include <hip/hip_cooperative_groups.h>

namespace cg = cooperative_groups;

// Problem constants (fixed by the reference).
#define BS 64
#define DX 512
#define DY 512
#define L (DX * DY)                 // 262144 bins per sample
#define TILE 4096                   // elements per tile
#define T_PER_S (L / TILE)          // 64 tiles per sample
#define THREADS 256
#define EPT (TILE / THREADS)        // 16 elements per thread
#define TPB 4                       // tiles per block (persistent mapping)
#define NBLK ((BS * T_PER_S) / TPB) // 1024 blocks = exactly 4/CU on 256 CUs
#define BLK_PER_S (T_PER_S / TPB)   // 16 blocks per sample

typedef float vfloat2 __attribute__((ext_vector_type(2)));
typedef float vfloat4 __attribute__((ext_vector_type(4)));

// ---------------------------------------------------------------------------
// Single cooperative kernel.
// Phase 1: each block counts nonzeros in its 4 owned tiles (lane-coalesced
//          float4 loads) -> tile_count[].
// grid.sync()
// Phase 2: wave 0 exclusive-scans the sample's 64 tile counts (L2-hot, 256 B)
//          -> s_off/len in LDS. Then per owned tile: re-read (same CU =>
//          same-XCD cache-warm), block-scan stable ranks, stage (idx,w) in
//          LDS, stream out coalesced NT stores, zero the tail stripe.
// LDS = 32.8 KiB => 4 blocks/CU co-resident (required for cooperative).
// ---------------------------------------------------------------------------
__global__ __launch_bounds__(THREADS, 4) void htpc_all(
    const float* __restrict__ hist, const float* __restrict__ x_lims,
    const float* __restrict__ y_lims, int* __restrict__ tile_count,
    float* __restrict__ out_pc, float* __restrict__ out_w,
    float* __restrict__ out_lens) {
  __shared__ int sidx[TILE];            // 16 KiB
  __shared__ float sw[TILE];            // 16 KiB
  __shared__ int s_off[T_PER_S + 1];    // exclusive offsets + total
  __shared__ int wsum[THREADS / 64];

  const int g = blockIdx.x;
  const int b = g / BLK_PER_S;          // sample
  const int tile0 = g * TPB;            // first owned tile (global id)
  const int lane = threadIdx.x & 63;
  const int wv = threadIdx.x >> 6;

  // ---- Phase 1: per-tile nonzero counts --------------------------------
  for (int tt = 0; tt < TPB; ++tt) {
    const int tile = tile0 + tt;
    const float4* h4 = (const float4*)(hist + (size_t)tile * TILE);
    int cnt = 0;
#pragma unroll
    for (int r = 0; r < EPT / 4; ++r) {
      float4 v = h4[r * THREADS + threadIdx.x];
      cnt += (v.x != 0.f) + (v.y != 0.f) + (v.z != 0.f) + (v.w != 0.f);
    }
#pragma unroll
    for (int d = 32; d > 0; d >>= 1) cnt += __shfl_down(cnt, d);
    if (lane == 0) wsum[wv] = cnt;
    __syncthreads();
    if (threadIdx.x == 0)
      tile_count[tile] = wsum[0] + wsum[1] + wsum[2] + wsum[3];
    __syncthreads();  // wsum reusable
  }

  __threadfence();          // make tile_count device-visible before the sync
  cg::this_grid().sync();

  // ---- Phase 2a: per-sample tile-offset scan (first wave) --------------
  if (threadIdx.x < 64) {
    const int c = tile_count[b * T_PER_S + threadIdx.x];
    int incl = c;
#pragma unroll
    for (int d = 1; d < 64; d <<= 1) {
      int n = __shfl_up(incl, d);
      if ((int)threadIdx.x >= d) incl += n;
    }
    s_off[threadIdx.x] = incl - c;  // exclusive
    if (threadIdx.x == 63) {
      s_off[T_PER_S] = incl;
      if ((g % BLK_PER_S) == 0) out_lens[b] = (float)incl;
    }
  }
  // visibility of s_off covered by the first __syncthreads in the loop below

  const float xlo = x_lims[b * 2], xhi = x_lims[b * 2 + 1];
  const float ylo = y_lims[b * 2], yhi = y_lims[b * 2 + 1];
  const float cxw = (xhi - xlo) / DX;
  const float cyw = (yhi - ylo) / DY;

  vfloat2* pc2 = (vfloat2*)out_pc + (size_t)b * L;  // pair units
  float* w = out_w + (size_t)b * L;

  // ---- Phase 2b: compact + tail-zero each owned tile -------------------
  for (int tt = 0; tt < TPB; ++tt) {
    const int tile = tile0 + tt;
    const int t = tile & (T_PER_S - 1);  // tile index within sample
    const size_t gbase = (size_t)tile * TILE + (size_t)threadIdx.x * EPT;
    const float4* h4 = (const float4*)(hist + gbase);

    // per-thread contiguous 16-elem chunk => thread order == row-major order
    float v[EPT];
#pragma unroll
    for (int i = 0; i < EPT / 4; ++i) {
      float4 a = h4[i];
      v[i * 4 + 0] = a.x;
      v[i * 4 + 1] = a.y;
      v[i * 4 + 2] = a.z;
      v[i * 4 + 3] = a.w;
    }
    int cnt = 0;
#pragma unroll
    for (int i = 0; i < EPT; ++i) cnt += (v[i] != 0.f);

    int incl = cnt;
#pragma unroll
    for (int d = 1; d < 64; d <<= 1) {
      int n = __shfl_up(incl, d);
      if (lane >= d) incl += n;
    }
    if (lane == 63) wsum[wv] = incl;
    __syncthreads();  // B1: wsum ready; s_off visible; prev stream-out done
    int wbase = 0, total = 0;
#pragma unroll
    for (int i = 0; i < THREADS / 64; ++i) {
      int s = wsum[i];
      if (i < wv) wbase += s;
      total += s;
    }
    int r = wbase + (incl - cnt);  // stable exclusive rank within tile

    const int lidx0 = (int)(gbase - (size_t)b * L);  // index within sample
#pragma unroll
    for (int i = 0; i < EPT; ++i) {
      if (v[i] != 0.f) {
        sidx[r] = lidx0 + i;
        sw[r] = v[i];
        ++r;
      }
    }
    const int off = s_off[t];
    const int len = s_off[T_PER_S];
    __syncthreads();  // B2: staging ready

    // coalesced nontemporal stream-out of the compacted run
    for (int k = threadIdx.x; k < total; k += THREADS) {
      const int idx = sidx[k];
      const int ix = idx >> 9;   // idx / DY
      const int iy = idx & 511;  // idx % DY
      vfloat2 p;
      p.x = xlo + cxw * ((float)ix + 0.5f);
      p.y = ylo + cyw * ((float)iy + 0.5f);
      __builtin_nontemporal_store(p, pc2 + (off + k));
      __builtin_nontemporal_store(sw[k], w + (off + k));
    }

    // zero this tile's output stripe ∩ [len, L), 16B-vectorized (verified R4)
    const int begin = t * TILE;
    const int end = begin + TILE;
    int s0 = (len > begin) ? len : begin;
    if (s0 < end) {
      int a0 = s0;
      if (a0 & 1) {
        if (threadIdx.x == 0) {
          const vfloat2 z2 = {0.f, 0.f};
          __builtin_nontemporal_store(z2, pc2 + a0);
        }
        ++a0;
      }
      {
        vfloat4* p4 = (vfloat4*)(pc2 + a0);
        const int n4 = (end - a0) >> 1;
        const vfloat4 z4 = {0.f, 0.f, 0.f, 0.f};
        for (int k = threadIdx.x; k < n4; k += THREADS)
          __builtin_nontemporal_store(z4, p4 + k);
      }
      const int head = (s0 + 3) & ~3;
      if (threadIdx.x < (head - s0) && (s0 + (int)threadIdx.x) < end)
        __builtin_nontemporal_store(0.f, w + s0 + threadIdx.x);
      if (head < end) {
        vfloat4* w4 = (vfloat4*)(w + head);
        const int n4 = (end - head) >> 2;
        const vfloat4 z4 = {0.f, 0.f, 0.f, 0.f};
        for (int k = threadIdx.x; k < n4; k += THREADS)
          __builtin_nontemporal_store(z4, w4 + k);
      }
    }
  }
}

extern "C" void kernel_launch(void* const* d_in, const int* in_sizes, int n_in,
                              void* d_out, int out_size, void* d_ws,
                              size_t ws_size, hipStream_t stream) {
  const float* hist = (const float*)d_in[0];    // [BS, DX, DY]
  const float* x_lims = (const float*)d_in[1];  // [BS, 2]
  const float* y_lims = (const float*)d_in[2];  // [BS, 2]

  float* out = (float*)d_out;
  float* out_pc = out;                          // [BS, L, 2]
  float* out_w = out + (size_t)BS * L * 2;      // [BS, L]
  float* out_lens = out_w + (size_t)BS * L;     // [BS] (as float32)

  int* tile_count = (int*)d_ws;                 // [BS * T_PER_S]

  void* args[] = {(void*)&hist, (void*)&x_lims, (void*)&y_lims,
                  (void*)&tile_count, (void*)&out_pc, (void*)&out_w,
                  (void*)&out_lens};
  hipLaunchCooperativeKernel((const void*)htpc_all, dim3(NBLK), dim3(THREADS),
                             args, 0, stream);
}

// Round 6
// 319.539 us; speedup vs baseline: 1.2482x; 1.2482x over previous
//
#include <hip/hip_runtime.h>

// Problem constants (fixed by the reference).
#define BS 64
#define DX 512
#define DY 512
#define L (DX * DY)                 // 262144 bins per sample
#define TILE 4096                   // elements per tile
#define T_PER_S (L / TILE)          // 64 tiles per sample
#define THREADS 256
#define EPT (TILE / THREADS)        // 16 elements per thread

typedef float vfloat2 __attribute__((ext_vector_type(2)));
typedef float vfloat4 __attribute__((ext_vector_type(4)));

// ---------------------------------------------------------------------------
// Phase 1: per-tile nonzero counts. Lane-consecutive float4 loads.
// ---------------------------------------------------------------------------
__global__ __launch_bounds__(THREADS) void htpc_count(
    const float* __restrict__ hist, int* __restrict__ tile_count) {
  const int tile = blockIdx.x;
  const float4* h4 = (const float4*)(hist + (size_t)tile * TILE);

  int cnt = 0;
#pragma unroll
  for (int r = 0; r < EPT / 4; ++r) {
    float4 v = h4[r * THREADS + threadIdx.x];
    cnt += (v.x != 0.f) + (v.y != 0.f) + (v.z != 0.f) + (v.w != 0.f);
  }
  const int lane = threadIdx.x & 63;
  const int wv = threadIdx.x >> 6;
#pragma unroll
  for (int d = 32; d > 0; d >>= 1) cnt += __shfl_down(cnt, d);
  __shared__ int ws[THREADS / 64];
  if (lane == 0) ws[wv] = cnt;
  __syncthreads();
  if (threadIdx.x == 0)
    tile_count[tile] = ws[0] + ws[1] + ws[2] + ws[3];
}

// ---------------------------------------------------------------------------
// Phase 2 (fused scan + direct-scatter compact + tail-zero).
// R5 post-mortem: LDS staging was latency-bound (ds round-trip + barrier +
// 33 KiB occupancy cap) and ~29 us SLOWER than the direct scatter (R1 vs R2
// ledger). Here: wave0 scans the sample's 64 tile counts (256 B, L2-hot),
// each thread block-scans its stable rank and scatters (x,y,w) straight to
// global. Scatter addresses are nearly-sorted (lanes ~10 elems apart) so L2
// write-combining absorbs them; regular stores (NT would force partial-line
// RMW). LDS ~300 B -> occupancy is VGPR-limited, no second barrier.
// ---------------------------------------------------------------------------
__global__ __launch_bounds__(THREADS) void htpc_scatter(
    const float* __restrict__ hist, const float* __restrict__ x_lims,
    const float* __restrict__ y_lims, const int* __restrict__ tile_count,
    float* __restrict__ out_pc, float* __restrict__ out_w,
    float* __restrict__ out_lens) {
  __shared__ int s_off[T_PER_S + 1];    // exclusive offsets + total
  __shared__ int wsum[THREADS / 64];

  const int tile = blockIdx.x;
  const int b = tile >> 6;   // tile / T_PER_S
  const int t = tile & 63;   // tile % T_PER_S
  const size_t gbase = (size_t)tile * TILE + (size_t)threadIdx.x * EPT;
  const float4* h4 = (const float4*)(hist + gbase);

  // issue tile loads early (per-thread contiguous 16-elem chunk => thread
  // order == row-major order => stable ranks)
  float v[EPT];
#pragma unroll
  for (int i = 0; i < EPT / 4; ++i) {
    float4 a = h4[i];
    v[i * 4 + 0] = a.x;
    v[i * 4 + 1] = a.y;
    v[i * 4 + 2] = a.z;
    v[i * 4 + 3] = a.w;
  }

  // (a) per-sample tile-offset scan, first wave only (wave-uniform branch)
  if (threadIdx.x < 64) {
    const int c = tile_count[b * T_PER_S + threadIdx.x];
    int incl = c;
#pragma unroll
    for (int d = 1; d < 64; d <<= 1) {
      int n = __shfl_up(incl, d);
      if ((int)threadIdx.x >= d) incl += n;
    }
    s_off[threadIdx.x] = incl - c;  // exclusive
    if (threadIdx.x == 63) {
      s_off[T_PER_S] = incl;
      if (t == 0) out_lens[b] = (float)incl;
    }
  }

  // (b) per-thread count + block exclusive scan (4 waves)
  int cnt = 0;
#pragma unroll
  for (int i = 0; i < EPT; ++i) cnt += (v[i] != 0.f);

  const int lane = threadIdx.x & 63;
  const int wv = threadIdx.x >> 6;
  int incl = cnt;
#pragma unroll
  for (int d = 1; d < 64; d <<= 1) {
    int n = __shfl_up(incl, d);
    if (lane >= d) incl += n;
  }
  if (lane == 63) wsum[wv] = incl;
  __syncthreads();  // covers s_off and wsum
  int wbase = 0;
#pragma unroll
  for (int i = 0; i < THREADS / 64; ++i)
    if (i < wv) wbase += wsum[i];

  // (c) direct stable scatter to global
  const float xlo = x_lims[b * 2], xhi = x_lims[b * 2 + 1];
  const float ylo = y_lims[b * 2], yhi = y_lims[b * 2 + 1];
  const float cxw = (xhi - xlo) / DX;
  const float cyw = (yhi - ylo) / DY;

  vfloat2* pc2 = (vfloat2*)out_pc + (size_t)b * L;  // pair units
  float* w = out_w + (size_t)b * L;
  const int len = s_off[T_PER_S];
  int pos = s_off[t] + wbase + (incl - cnt);  // stable global rank

  const int lidx0 = (int)(gbase - (size_t)b * L);  // index within sample
#pragma unroll
  for (int i = 0; i < EPT; ++i) {
    if (v[i] != 0.f) {
      const int idx = lidx0 + i;
      const int ix = idx >> 9;   // idx / DY
      const int iy = idx & 511;  // idx % DY
      vfloat2 p;
      p.x = xlo + cxw * ((float)ix + 0.5f);
      p.y = ylo + cyw * ((float)iy + 0.5f);
      pc2[pos] = p;
      w[pos] = v[i];
      ++pos;
    }
  }

  // (d) zero this tile's output stripe ∩ [len, L), 16B NT stores (verified)
  const int begin = t * TILE;
  const int end = begin + TILE;
  int s0 = (len > begin) ? len : begin;
  if (s0 < end) {
    int a0 = s0;
    if (a0 & 1) {
      if (threadIdx.x == 0) {
        const vfloat2 z2 = {0.f, 0.f};
        __builtin_nontemporal_store(z2, pc2 + a0);
      }
      ++a0;
    }
    {
      vfloat4* p4 = (vfloat4*)(pc2 + a0);
      const int n4 = (end - a0) >> 1;
      const vfloat4 z4 = {0.f, 0.f, 0.f, 0.f};
      for (int k = threadIdx.x; k < n4; k += THREADS)
        __builtin_nontemporal_store(z4, p4 + k);
    }
    const int head = (s0 + 3) & ~3;
    if (threadIdx.x < (head - s0) && (s0 + (int)threadIdx.x) < end)
      __builtin_nontemporal_store(0.f, w + s0 + threadIdx.x);
    if (head < end) {
      vfloat4* w4 = (vfloat4*)(w + head);
      const int n4 = (end - head) >> 2;
      const vfloat4 z4 = {0.f, 0.f, 0.f, 0.f};
      for (int k = threadIdx.x; k < n4; k += THREADS)
        __builtin_nontemporal_store(z4, w4 + k);
    }
  }
}

extern "C" void kernel_launch(void* const* d_in, const int* in_sizes, int n_in,
                              void* d_out, int out_size, void* d_ws,
                              size_t ws_size, hipStream_t stream) {
  const float* hist = (const float*)d_in[0];    // [BS, DX, DY]
  const float* x_lims = (const float*)d_in[1];  // [BS, 2]
  const float* y_lims = (const float*)d_in[2];  // [BS, 2]

  float* out = (float*)d_out;
  float* out_pc = out;                          // [BS, L, 2]
  float* out_w = out + (size_t)BS * L * 2;      // [BS, L]
  float* out_lens = out_w + (size_t)BS * L;     // [BS] (as float32)

  int* tile_count = (int*)d_ws;                 // [BS * T_PER_S]

  htpc_count<<<BS * T_PER_S, THREADS, 0, stream>>>(hist, tile_count);
  htpc_scatter<<<BS * T_PER_S, THREADS, 0, stream>>>(
      hist, x_lims, y_lims, tile_count, out_pc, out_w, out_lens);
}

// Round 7
// 257.094 us; speedup vs baseline: 1.5514x; 1.2429x over previous
//
#include <hip/hip_runtime.h>

// Problem constants (fixed by the reference).
#define BS 64
#define DX 512
#define DY 512
#define L (DX * DY)                 // 262144 bins per sample
#define TILE 4096                   // elements per tile
#define T_PER_S (L / TILE)          // 64 tiles per sample
#define THREADS 256
#define EPT (TILE / THREADS)        // 16 elements per thread

typedef float vfloat2 __attribute__((ext_vector_type(2)));
typedef float vfloat4 __attribute__((ext_vector_type(4)));

// ---------------------------------------------------------------------------
// Phase 1: per-tile nonzero counts. Lane-consecutive float4 loads.
// ---------------------------------------------------------------------------
__global__ __launch_bounds__(THREADS) void htpc_count(
    const float* __restrict__ hist, int* __restrict__ tile_count) {
  const int tile = blockIdx.x;
  const float4* h4 = (const float4*)(hist + (size_t)tile * TILE);

  int cnt = 0;
#pragma unroll
  for (int r = 0; r < EPT / 4; ++r) {
    float4 v = h4[r * THREADS + threadIdx.x];
    cnt += (v.x != 0.f) + (v.y != 0.f) + (v.z != 0.f) + (v.w != 0.f);
  }
  const int lane = threadIdx.x & 63;
  const int wv = threadIdx.x >> 6;
#pragma unroll
  for (int d = 32; d > 0; d >>= 1) cnt += __shfl_down(cnt, d);
  __shared__ int ws[THREADS / 64];
  if (lane == 0) ws[wv] = cnt;
  __syncthreads();
  if (threadIdx.x == 0)
    tile_count[tile] = ws[0] + ws[1] + ws[2] + ws[3];
}

// ---------------------------------------------------------------------------
// Phase 2 (fused scan + LDS-staged compact + tail-zero) — R4 structure
// (A/B-verified faster than direct scatter in R6), with the stream-out
// 16B-packed: 2 (x,y) pairs per dwordx4 store, 4 weights per dwordx4 store.
// Store-instruction count for the compact region drops ~2.7x.
// ---------------------------------------------------------------------------
__global__ __launch_bounds__(THREADS) void htpc_fused(
    const float* __restrict__ hist, const float* __restrict__ x_lims,
    const float* __restrict__ y_lims, const int* __restrict__ tile_count,
    float* __restrict__ out_pc, float* __restrict__ out_w,
    float* __restrict__ out_lens) {
  __shared__ int sidx[TILE];            // 16 KiB
  __shared__ float sw[TILE];            // 16 KiB
  __shared__ int s_off[T_PER_S + 1];    // exclusive offsets + total
  __shared__ int wsum[THREADS / 64];

  const int tile = blockIdx.x;
  const int b = tile >> 6;   // tile / T_PER_S
  const int t = tile & 63;   // tile % T_PER_S
  const size_t gbase = (size_t)tile * TILE + (size_t)threadIdx.x * EPT;
  const float4* h4 = (const float4*)(hist + gbase);

  // per-thread contiguous 16-elem chunk => thread order == row-major order
  float v[EPT];
#pragma unroll
  for (int i = 0; i < EPT / 4; ++i) {
    float4 a = h4[i];
    v[i * 4 + 0] = a.x;
    v[i * 4 + 1] = a.y;
    v[i * 4 + 2] = a.z;
    v[i * 4 + 3] = a.w;
  }

  // (a) per-sample tile-offset scan, first wave only (wave-uniform branch)
  if (threadIdx.x < 64) {
    const int c = tile_count[b * T_PER_S + threadIdx.x];
    int incl = c;
#pragma unroll
    for (int d = 1; d < 64; d <<= 1) {
      int n = __shfl_up(incl, d);
      if ((int)threadIdx.x >= d) incl += n;
    }
    s_off[threadIdx.x] = incl - c;  // exclusive
    if (threadIdx.x == 63) {
      s_off[T_PER_S] = incl;
      if (t == 0) out_lens[b] = (float)incl;
    }
  }

  // (b) per-thread counts + block exclusive scan (4 waves)
  int cnt = 0;
#pragma unroll
  for (int i = 0; i < EPT; ++i) cnt += (v[i] != 0.f);

  const int lane = threadIdx.x & 63;
  const int wv = threadIdx.x >> 6;
  int incl = cnt;
#pragma unroll
  for (int d = 1; d < 64; d <<= 1) {
    int n = __shfl_up(incl, d);
    if (lane >= d) incl += n;
  }
  if (lane == 63) wsum[wv] = incl;
  __syncthreads();  // covers s_off and wsum
  int wbase = 0, total = 0;
#pragma unroll
  for (int i = 0; i < THREADS / 64; ++i) {
    int s = wsum[i];
    if (i < wv) wbase += s;
    total += s;
  }
  int r = wbase + (incl - cnt);  // stable exclusive rank within tile

  const int lidx0 = (int)(gbase - (size_t)b * L);  // index within sample
#pragma unroll
  for (int i = 0; i < EPT; ++i) {
    if (v[i] != 0.f) {
      sidx[r] = lidx0 + i;
      sw[r] = v[i];
      ++r;
    }
  }
  const int off = s_off[t];
  const int len = s_off[T_PER_S];
  __syncthreads();  // staging ready

  // (c) 16B-packed coalesced nontemporal stream-out
  const float xlo = x_lims[b * 2], xhi = x_lims[b * 2 + 1];
  const float ylo = y_lims[b * 2], yhi = y_lims[b * 2 + 1];
  const float cxw = (xhi - xlo) / DX;
  const float cyw = (yhi - ylo) / DY;

  vfloat2* pc2 = (vfloat2*)out_pc + (size_t)b * L;  // pair units
  float* w = out_w + (size_t)b * L;

  if (total > 0) {
    // ---- pc pairs: head (odd off), dwordx4 body (2 pairs), odd tail ----
    const int ho = off & 1;  // 0/1 head pairs
    if (ho && threadIdx.x == 0) {
      const int idx = sidx[0];
      vfloat2 p;
      p.x = xlo + cxw * ((float)(idx >> 9) + 0.5f);
      p.y = ylo + cyw * ((float)(idx & 511) + 0.5f);
      pc2[off] = p;
    }
    const int remp = total - ho;     // >= 0 (ho<=1<=total)
    const int nb = remp >> 1;
    for (int k = threadIdx.x; k < nb; k += THREADS) {
      const int s = ho + 2 * k;
      const int i0 = sidx[s], i1 = sidx[s + 1];
      vfloat4 q;
      q.x = xlo + cxw * ((float)(i0 >> 9) + 0.5f);
      q.y = ylo + cyw * ((float)(i0 & 511) + 0.5f);
      q.z = xlo + cxw * ((float)(i1 >> 9) + 0.5f);
      q.w = ylo + cyw * ((float)(i1 & 511) + 0.5f);
      __builtin_nontemporal_store(q, (vfloat4*)(pc2 + off + s));
    }
    if ((remp & 1) && threadIdx.x == 0) {
      const int s = ho + 2 * nb;
      const int idx = sidx[s];
      vfloat2 p;
      p.x = xlo + cxw * ((float)(idx >> 9) + 0.5f);
      p.y = ylo + cyw * ((float)(idx & 511) + 0.5f);
      pc2[off + s] = p;
    }

    // ---- w: scalar head to 16B alignment, dwordx4 body, scalar tail ----
    const int hw0 = (4 - (off & 3)) & 3;
    const int hw = hw0 < total ? hw0 : total;
    if ((int)threadIdx.x < hw) w[off + threadIdx.x] = sw[threadIdx.x];
    const int remw = total - hw;
    const int nw = remw >> 2;
    const float* swb = sw + hw;
    float* wb = w + off + hw;
    for (int k = threadIdx.x; k < nw; k += THREADS) {
      vfloat4 q;
      q.x = swb[4 * k + 0];
      q.y = swb[4 * k + 1];
      q.z = swb[4 * k + 2];
      q.w = swb[4 * k + 3];
      __builtin_nontemporal_store(q, (vfloat4*)wb + k);
    }
    const int tw = remw & 3;
    if ((int)threadIdx.x < tw)
      wb[4 * nw + threadIdx.x] = swb[4 * nw + threadIdx.x];
  }

  // (d) zero this tile's output stripe ∩ [len, L), 16B NT stores (verified)
  const int begin = t * TILE;
  const int end = begin + TILE;
  int s0 = (len > begin) ? len : begin;
  if (s0 < end) {
    int a0 = s0;
    if (a0 & 1) {
      if (threadIdx.x == 0) {
        const vfloat2 z2 = {0.f, 0.f};
        __builtin_nontemporal_store(z2, pc2 + a0);
      }
      ++a0;
    }
    {
      vfloat4* p4 = (vfloat4*)(pc2 + a0);
      const int n4 = (end - a0) >> 1;
      const vfloat4 z4 = {0.f, 0.f, 0.f, 0.f};
      for (int k = threadIdx.x; k < n4; k += THREADS)
        __builtin_nontemporal_store(z4, p4 + k);
    }
    const int head = (s0 + 3) & ~3;
    if ((int)threadIdx.x < (head - s0) && (s0 + (int)threadIdx.x) < end)
      __builtin_nontemporal_store(0.f, w + s0 + threadIdx.x);
    if (head < end) {
      vfloat4* w4 = (vfloat4*)(w + head);
      const int n4 = (end - head) >> 2;
      const vfloat4 z4 = {0.f, 0.f, 0.f, 0.f};
      for (int k = threadIdx.x; k < n4; k += THREADS)
        __builtin_nontemporal_store(z4, w4 + k);
    }
  }
}

extern "C" void kernel_launch(void* const* d_in, const int* in_sizes, int n_in,
                              void* d_out, int out_size, void* d_ws,
                              size_t ws_size, hipStream_t stream) {
  const float* hist = (const float*)d_in[0];    // [BS, DX, DY]
  const float* x_lims = (const float*)d_in[1];  // [BS, 2]
  const float* y_lims = (const float*)d_in[2];  // [BS, 2]

  float* out = (float*)d_out;
  float* out_pc = out;                          // [BS, L, 2]
  float* out_w = out + (size_t)BS * L * 2;      // [BS, L]
  float* out_lens = out_w + (size_t)BS * L;     // [BS] (as float32)

  int* tile_count = (int*)d_ws;                 // [BS * T_PER_S]

  htpc_count<<<BS * T_PER_S, THREADS, 0, stream>>>(hist, tile_count);
  htpc_fused<<<BS * T_PER_S, THREADS, 0, stream>>>(
      hist, x_lims, y_lims, tile_count, out_pc, out_w, out_lens);
}

// Round 8
// 255.758 us; speedup vs baseline: 1.5595x; 1.0052x over previous
//
#include <hip/hip_runtime.h>

// Problem constants (fixed by the reference).
#define BS 64
#define DX 512
#define DY 512
#define L (DX * DY)                 // 262144 bins per sample
#define TILE 1024                   // elements per tile (= THREADS * EPT)
#define T_PER_S (L / TILE)          // 256 tiles per sample
#define THREADS 256
#define EPT 4                       // one float4 per thread: chunk == vector
#define NTILES (BS * T_PER_S)       // 16384

typedef float vfloat2 __attribute__((ext_vector_type(2)));
typedef float vfloat4 __attribute__((ext_vector_type(4)));

// ---------------------------------------------------------------------------
// Phase 1: per-tile nonzero counts. One float4 per thread, lane-consecutive
// (fully coalesced: 16 lines/instr, 4 lanes/line).
// ---------------------------------------------------------------------------
__global__ __launch_bounds__(THREADS) void htpc_count(
    const float* __restrict__ hist, int* __restrict__ tile_count) {
  const int tile = blockIdx.x;
  const float4 a = ((const float4*)(hist + (size_t)tile * TILE))[threadIdx.x];
  int cnt = (a.x != 0.f) + (a.y != 0.f) + (a.z != 0.f) + (a.w != 0.f);

  const int lane = threadIdx.x & 63;
  const int wv = threadIdx.x >> 6;
#pragma unroll
  for (int d = 32; d > 0; d >>= 1) cnt += __shfl_down(cnt, d);
  __shared__ int ws[THREADS / 64];
  if (lane == 0) ws[wv] = cnt;
  __syncthreads();
  if (threadIdx.x == 0)
    tile_count[tile] = ws[0] + ws[1] + ws[2] + ws[3];
}

// ---------------------------------------------------------------------------
// Phase 2: fused scan + compact + tail-zero, one block per 1024-elem tile.
// Per-thread chunk = one float4 => hist load is lane-consecutive AND
// thread-contiguous (stable ranks, zero transaction inflation).
// The per-sample tile-offset scan (256 entries, thread i <-> tile i) and the
// per-thread rank scan are fused into ONE packed 64-bit block scan:
//   val = (tile_count << 32) | own_cnt   (sums fit: <=262144 / <=1024).
// ---------------------------------------------------------------------------
__global__ __launch_bounds__(THREADS) void htpc_fused(
    const float* __restrict__ hist, const float* __restrict__ x_lims,
    const float* __restrict__ y_lims, const int* __restrict__ tile_count,
    float* __restrict__ out_pc, float* __restrict__ out_w,
    float* __restrict__ out_lens) {
  __shared__ int sidx[TILE];                       // 4 KiB
  __shared__ float sw[TILE];                       // 4 KiB
  __shared__ unsigned long long wsum[THREADS / 64];
  __shared__ int s_off_mine;

  const int g = blockIdx.x;
  const int b = g >> 8;        // sample
  const int t = g & 255;       // tile within sample
  const int tid = threadIdx.x;

  // own float4 (chunk == vector)
  const float4 a = ((const float4*)(hist + (size_t)g * TILE))[tid];
  float v[EPT] = {a.x, a.y, a.z, a.w};
  int cnt = (v[0] != 0.f) + (v[1] != 0.f) + (v[2] != 0.f) + (v[3] != 0.f);

  // tile count for the sample-wide offset scan (thread i <-> tile i)
  const int c_tile = tile_count[b * T_PER_S + tid];

  // packed 64-bit block inclusive scan over 256 threads
  const int lane = tid & 63;
  const int wv = tid >> 6;
  unsigned long long val =
      ((unsigned long long)(unsigned)c_tile << 32) | (unsigned)cnt;
  unsigned long long incl = val;
#pragma unroll
  for (int d = 1; d < 64; d <<= 1) {
    unsigned long long n = __shfl_up(incl, d);
    if (lane >= d) incl += n;
  }
  if (lane == 63) wsum[wv] = incl;
  __syncthreads();
  unsigned long long wbase = 0, total = 0;
#pragma unroll
  for (int i = 0; i < THREADS / 64; ++i) {
    unsigned long long s = wsum[i];
    if (i < wv) wbase += s;
    total += s;
  }
  const unsigned long long ex = wbase + incl - val;  // exclusive prefix @tid
  int r = (int)(ex & 0xffffffffu);              // stable rank within tile
  const int offpref = (int)(ex >> 32);          // tile-offset prefix @tid
  const int len = (int)(total >> 32);           // sample nonzero count
  const int total_cnt = (int)(total & 0xffffffffu);  // nonzeros in this tile

  if (tid == t) s_off_mine = offpref;           // broadcast our tile's offset
  if (t == 0 && tid == 0) out_lens[b] = (float)len;

  // stage (idx, w) at stable ranks
  const int lidx0 = t * TILE + tid * EPT;       // index within sample
#pragma unroll
  for (int i = 0; i < EPT; ++i) {
    if (v[i] != 0.f) {
      sidx[r] = lidx0 + i;
      sw[r] = v[i];
      ++r;
    }
  }
  __syncthreads();  // staging + s_off_mine ready
  const int off = s_off_mine;

  // center-grid params: cx[j] = xlo + cxw*(j+0.5)
  const float xlo = x_lims[b * 2], xhi = x_lims[b * 2 + 1];
  const float ylo = y_lims[b * 2], yhi = y_lims[b * 2 + 1];
  const float cxw = (xhi - xlo) / DX;
  const float cyw = (yhi - ylo) / DY;

  vfloat2* pc2 = (vfloat2*)out_pc + (size_t)b * L;  // pair units
  float* w = out_w + (size_t)b * L;

  if (total_cnt > 0) {
    // ---- pc pairs: head (odd off), dwordx4 body (2 pairs), odd tail ----
    const int ho = off & 1;
    if (ho && tid == 0) {
      const int idx = sidx[0];
      vfloat2 p;
      p.x = xlo + cxw * ((float)(idx >> 9) + 0.5f);
      p.y = ylo + cyw * ((float)(idx & 511) + 0.5f);
      pc2[off] = p;
    }
    const int remp = total_cnt - ho;
    const int nb = remp >> 1;
    for (int k = tid; k < nb; k += THREADS) {
      const int s = ho + 2 * k;
      const int i0 = sidx[s], i1 = sidx[s + 1];
      vfloat4 q;
      q.x = xlo + cxw * ((float)(i0 >> 9) + 0.5f);
      q.y = ylo + cyw * ((float)(i0 & 511) + 0.5f);
      q.z = xlo + cxw * ((float)(i1 >> 9) + 0.5f);
      q.w = ylo + cyw * ((float)(i1 & 511) + 0.5f);
      __builtin_nontemporal_store(q, (vfloat4*)(pc2 + off + s));
    }
    if ((remp & 1) && tid == 0) {
      const int s = ho + 2 * nb;
      const int idx = sidx[s];
      vfloat2 p;
      p.x = xlo + cxw * ((float)(idx >> 9) + 0.5f);
      p.y = ylo + cyw * ((float)(idx & 511) + 0.5f);
      pc2[off + s] = p;
    }

    // ---- w: scalar head to 16B alignment, dwordx4 body, scalar tail ----
    const int hw0 = (4 - (off & 3)) & 3;
    const int hw = hw0 < total_cnt ? hw0 : total_cnt;
    if (tid < hw) w[off + tid] = sw[tid];
    const int remw = total_cnt - hw;
    const int nw = remw >> 2;
    const float* swb = sw + hw;
    float* wb = w + off + hw;
    for (int k = tid; k < nw; k += THREADS) {
      vfloat4 q;
      q.x = swb[4 * k + 0];
      q.y = swb[4 * k + 1];
      q.z = swb[4 * k + 2];
      q.w = swb[4 * k + 3];
      __builtin_nontemporal_store(q, (vfloat4*)wb + k);
    }
    const int tw = remw & 3;
    if (tid < tw) wb[4 * nw + tid] = swb[4 * nw + tid];
  }

  // tail-zero this tile's output stripe ∩ [len, L), 16B NT stores (verified)
  const int begin = t * TILE;
  const int end = begin + TILE;
  int s0 = (len > begin) ? len : begin;
  if (s0 < end) {
    int a0 = s0;
    if (a0 & 1) {
      if (tid == 0) {
        const vfloat2 z2 = {0.f, 0.f};
        __builtin_nontemporal_store(z2, pc2 + a0);
      }
      ++a0;
    }
    {
      vfloat4* p4 = (vfloat4*)(pc2 + a0);
      const int n4 = (end - a0) >> 1;
      const vfloat4 z4 = {0.f, 0.f, 0.f, 0.f};
      for (int k = tid; k < n4; k += THREADS)
        __builtin_nontemporal_store(z4, p4 + k);
    }
    const int head = (s0 + 3) & ~3;
    if (tid < (head - s0) && (s0 + tid) < end)
      __builtin_nontemporal_store(0.f, w + s0 + tid);
    if (head < end) {
      vfloat4* w4 = (vfloat4*)(w + head);
      const int n4 = (end - head) >> 2;
      const vfloat4 z4 = {0.f, 0.f, 0.f, 0.f};
      for (int k = tid; k < n4; k += THREADS)
        __builtin_nontemporal_store(z4, w4 + k);
    }
  }
}

extern "C" void kernel_launch(void* const* d_in, const int* in_sizes, int n_in,
                              void* d_out, int out_size, void* d_ws,
                              size_t ws_size, hipStream_t stream) {
  const float* hist = (const float*)d_in[0];    // [BS, DX, DY]
  const float* x_lims = (const float*)d_in[1];  // [BS, 2]
  const float* y_lims = (const float*)d_in[2];  // [BS, 2]

  float* out = (float*)d_out;
  float* out_pc = out;                          // [BS, L, 2]
  float* out_w = out + (size_t)BS * L * 2;      // [BS, L]
  float* out_lens = out_w + (size_t)BS * L;     // [BS] (as float32)

  int* tile_count = (int*)d_ws;                 // [NTILES]

  htpc_count<<<NTILES, THREADS, 0, stream>>>(hist, tile_count);
  htpc_fused<<<NTILES, THREADS, 0, stream>>>(
      hist, x_lims, y_lims, tile_count, out_pc, out_w, out_lens);
}